// Round 6
// baseline (819.247 us; speedup 1.0000x reference)
//
#include <hip/hip_runtime.h>

#define Bb 16
#define Lq 2048
#define Dd 64
#define QT 16
#define NT 512
#define NWAVE 8
#define KCH 256

typedef _Float16 f16x2 __attribute__((ext_vector_type(2)));
typedef _Float16 f16x8 __attribute__((ext_vector_type(8)));
typedef __attribute__((ext_vector_type(4))) float f32x4;
typedef __attribute__((ext_vector_type(2))) float f32x2;
typedef __attribute__((ext_vector_type(4))) unsigned int u32x4;
typedef __attribute__((ext_vector_type(4))) int i32x4;

union H8 { f16x8 v8; f16x2 h2[4]; unsigned int u[4]; u32x4 u4; };
union H1 { f16x2 h; unsigned int u; };

__device__ __forceinline__ f16x2 pkrtz(float a, float b) {
  return __builtin_bit_cast(f16x2, __builtin_amdgcn_cvt_pkrtz(a, b));
}
__device__ __forceinline__ f32x4 MF16(f16x8 a, f16x8 b, f32x4 c) {
  return __builtin_amdgcn_mfma_f32_16x16x32_f16(a, b, c, 0, 0, 0);
}
__device__ __forceinline__ f32x4 MFu(u32x4 a, const H8& b, f32x4 c) {
  return MF16(__builtin_bit_cast(f16x8, a), b.v8, c);
}

// ---------------- prep: K -> f16 h/l split planes (A-frag order);
//                  V -> f16-pair tiles in exact B-frag order ----------------
__global__ __launch_bounds__(256)
void sdpa_prep(const float* __restrict__ kg, const float* __restrict__ vg,
               u32x4* __restrict__ Kh, u32x4* __restrict__ Kl,
               u32x4* __restrict__ Vq)
{
  const int t = threadIdx.x, blk = blockIdx.x;
  if (blk < 1024) {                        // K part: 32 rows/block, 8 thr/row
    const int row = blk * 32 + (t >> 3);   // global row in [0, 16*2048)
    const int d8  = t & 7;                 // dims 8*d8 .. 8*d8+7
    const float* kp = kg + (size_t)row * Dd + d8 * 8;
    f32x4 a = *(const f32x4*)kp;
    f32x4 c = *(const f32x4*)(kp + 4);
    H1 h0, h1, h2, h3, l0, l1, l2, l3;
    h0.h = pkrtz(a.x, a.y); l0.h = pkrtz(a.x - (float)h0.h.x, a.y - (float)h0.h.y);
    h1.h = pkrtz(a.z, a.w); l1.h = pkrtz(a.z - (float)h1.h.x, a.w - (float)h1.h.y);
    h2.h = pkrtz(c.x, c.y); l2.h = pkrtz(c.x - (float)h2.h.x, c.y - (float)h2.h.y);
    h3.h = pkrtz(c.z, c.w); l3.h = pkrtz(c.z - (float)h3.h.x, c.w - (float)h3.h.y);
    u32x4 hh = {h0.u, h1.u, h2.u, h3.u};
    u32x4 ll = {l0.u, l1.u, l2.u, l3.u};
    Kh[(size_t)row * 8 + d8] = hh;
    Kl[(size_t)row * 8 + d8] = ll;
  } else {                                 // V part: one B-frag u32x4/thread
    const int v_ = (blk - 1024) * 256 + t; // [0, 262144)
    const int ln = v_ & 15, nt = (v_ >> 4) & 3, u = (v_ >> 6) & 3;
    const int g = (v_ >> 8) & 7, w = (v_ >> 11) & 7, b = v_ >> 14;
    const int R = w * KCH + g * 32 + u * 4;
    const float* vp = vg + ((size_t)b * Lq + R) * Dd + nt * 16 + ln;
    H1 p0, p1, p2, p3;
    p0.h = pkrtz(vp[0 * Dd],  vp[1 * Dd]);
    p1.h = pkrtz(vp[2 * Dd],  vp[3 * Dd]);
    p2.h = pkrtz(vp[16 * Dd], vp[17 * Dd]);
    p3.h = pkrtz(vp[18 * Dd], vp[19 * Dd]);
    u32x4 o = {p0.u, p1.u, p2.u, p3.u};
    Vq[v_] = o;
  }
}

// ---------------- main kernel (templated for ablation) ----------------
template<bool DO_PV, bool DO_AST, bool DO_MASK, bool SINK>
__global__ __launch_bounds__(NT, 2)
void sdpa_main(const float* __restrict__ qg,
               const u32x4* __restrict__ Khp, const u32x4* __restrict__ Klp,
               const u32x4* __restrict__ Vqp, const int* __restrict__ mg,
               float* __restrict__ outO, float* __restrict__ outA)
{
  __shared__ unsigned int Qh[QT][36], Ql[QT][36];
  __shared__ float red[QT][NWAVE];
  __shared__ float dinv_s[QT];
  __shared__ float Ored[NWAVE][QT][66];

  const int tid = threadIdx.x;
  const int l   = tid & 63;
  const int ln  = l & 15;
  const int u   = l >> 4;
  const int w   = tid >> 6;
  const int bid = (int)(blockIdx.x % 8) * 256 + (int)(blockIdx.x / 8);
  const int b   = bid >> 7;
  const int q0  = (bid & 127) * QT;
  const int kb  = w * KCH;

  // Phase 0: Q tile -> f16 h/l split planes in LDS
  {
    int r = tid >> 5, d2 = tid & 31;
    f32x2 qv = *(const f32x2*)(qg + (size_t)(b * Lq + q0 + r) * Dd + 2 * d2);
    H1 h, lo;
    h.h  = pkrtz(qv.x, qv.y);
    lo.h = pkrtz(qv.x - (float)h.h.x, qv.y - (float)h.h.y);
    Qh[r][d2] = h.u;
    Ql[r][d2] = lo.u;
  }
  __syncthreads();

  H8 Bh[2], Bl[2];
#pragma unroll
  for (int s = 0; s < 2; ++s) {
    Bh[s].u4 = *(const u32x4*)&Qh[ln][16 * s + 4 * u];
    Bl[s].u4 = *(const u32x4*)&Ql[ln][16 * s + 4 * u];
  }

  // Phase 1: S = K.Q^T (hh+hl+lh f16 MFMA), prefetched dwordx4 K-frag loads
  const u32x4* khB = Khp + ((size_t)b * Lq + kb + ln) * 8 + u;  // [128*t + 4*s]
  const u32x4* klB = Klp + ((size_t)b * Lq + kb + ln) * 8 + u;
  const int*   mbase = mg + (size_t)(b * Lq + q0 + ln) * Lq + kb + 4 * u;

  unsigned int su[16][2];
  float rs = 0.f;
  u32x4 nh0 = khB[0], nh1 = khB[4];
  u32x4 nl0 = klB[0], nl1 = klB[4];
  i32x4 nm = {0, 0, 0, 0};
  if (DO_MASK) nm = *(const i32x4*)mbase;

#pragma unroll
  for (int t = 0; t < 16; ++t) {
    u32x4 h0 = nh0, h1 = nh1, l0 = nl0, l1 = nl1;
    i32x4 mm = nm;
    if (t < 15) {
      nh0 = khB[128 * (t + 1)];     nh1 = khB[128 * (t + 1) + 4];
      nl0 = klB[128 * (t + 1)];     nl1 = klB[128 * (t + 1) + 4];
      if (DO_MASK) nm = *(const i32x4*)(mbase + (t + 1) * 16);
    }
    f32x4 acc = {0.f, 0.f, 0.f, 0.f};
    acc = MFu(h0, Bh[0], acc);
    acc = MFu(h0, Bl[0], acc);
    acc = MFu(l0, Bh[0], acc);
    acc = MFu(h1, Bh[1], acc);
    acc = MFu(h1, Bl[1], acc);
    acc = MFu(l1, Bh[1], acc);
    float s0 = mm.x ? 0.f : acc.x;
    float s1 = mm.y ? 0.f : acc.y;
    float s2 = mm.z ? 0.f : acc.z;
    float s3 = mm.w ? 0.f : acc.w;
    rs += (s0 + s1) + (s2 + s3);
    H1 p0, p1;
    p0.h = pkrtz(s0, s1); p1.h = pkrtz(s2, s3);
    su[t][0] = p0.u; su[t][1] = p1.u;
  }

  // Phase 2: row-sum -> dinv
  rs += __shfl_xor(rs, 16);
  rs += __shfl_xor(rs, 32);
  if (l < 16) red[l][w] = rs;
  __syncthreads();
  f32x4 r0 = *(const f32x4*)&red[ln][0];
  f32x4 r1 = *(const f32x4*)&red[ln][4];
  float sum = ((r0.x + r0.y) + (r0.z + r0.w)) + ((r1.x + r1.y) + (r1.z + r1.w));
  float dinv = 1.0f / fmaxf(sum, 1e-14f);
  if (w == 0 && l < 16) dinv_s[l] = dinv;

  // Phase 4: PV via pre-packed Vq (one coalesced dwordx4 per MFMA)
  f32x4 pv[4] = {{0,0,0,0},{0,0,0,0},{0,0,0,0},{0,0,0,0}};
  if (DO_PV) {
    const u32x4* vq = Vqp + (size_t)(b * 8 + w) * 2048;
#pragma unroll
    for (int g = 0; g < 8; ++g) {
      H8 aw;
      aw.u[0] = su[2 * g][0];     aw.u[1] = su[2 * g][1];
      aw.u[2] = su[2 * g + 1][0]; aw.u[3] = su[2 * g + 1][1];
#pragma unroll
      for (int nt = 0; nt < 4; ++nt) {
        u32x4 bw = vq[((g * 4 + u) * 4 + nt) * 16 + ln];
        pv[nt] = MF16(aw.v8, __builtin_bit_cast(f16x8, bw), pv[nt]);
      }
    }
  }

  // Phase 3: attn stores (after PV issue so PV's waitcnt isn't behind stores)
  if (DO_AST) {
#pragma unroll
    for (int t = 0; t < 16; ++t) {
      H1 p0, p1; p0.u = su[t][0]; p1.u = su[t][1];
      f32x4 st = {(float)p0.h.x * dinv, (float)p0.h.y * dinv,
                  (float)p1.h.x * dinv, (float)p1.h.y * dinv};
      size_t idx = (size_t)(b * Lq + q0 + ln) * Lq + kb + 16 * t + 4 * u;
      if (SINK) idx = (size_t)((unsigned)idx & 0xFFFFCu);   // wrap into 4MB sink
      *(f32x4*)(outA + idx) = st;
    }
  }

  // Phase 5: cross-wave O reduce + store
  if (DO_PV) {
#pragma unroll
    for (int nt = 0; nt < 4; ++nt)
#pragma unroll
      for (int r = 0; r < 4; ++r)
        Ored[w][u * 4 + r][nt * 16 + ln] = pv[nt][r];
    __syncthreads();
    {
      int q = tid >> 5, d = (tid & 31) * 2;
      float o0 = 0.f, o1 = 0.f;
#pragma unroll
      for (int ww = 0; ww < NWAVE; ++ww) {
        o0 += Ored[ww][q][d];
        o1 += Ored[ww][q][d + 1];
      }
      float dv = dinv_s[q];
      f32x2 st = {o0 * dv, o1 * dv};
      size_t idx = (size_t)(b * Lq + q0 + q) * Dd + d;
      if (SINK) idx = (size_t)((unsigned)idx & 0xFFFFEu);
      *(f32x2*)(outO + idx) = st;
    }
  }
}

// ---------------- legacy fallback (R5 kernel, known-passing) ----------------
__global__ __launch_bounds__(NT, 4)
void sdpa_legacy(const float* __restrict__ qg, const float* __restrict__ kg,
                 const float* __restrict__ vg, const int* __restrict__ mg,
                 float* __restrict__ outO, float* __restrict__ outA)
{
  __shared__ unsigned int Qh[QT][36], Ql[QT][36];
  __shared__ float red[QT][NWAVE];
  __shared__ float dinv_s[QT];
  __shared__ float Ored[NWAVE][QT][66];

  const int tid = threadIdx.x;
  const int l   = tid & 63;
  const int ln  = l & 15;
  const int u   = l >> 4;
  const int w   = tid >> 6;
  const int bid = (int)(blockIdx.x % 8) * 256 + (int)(blockIdx.x / 8);
  const int b   = bid >> 7;
  const int q0  = (bid & 127) * QT;
  const int kb  = w * KCH;

  {
    int r = tid >> 5, d2 = tid & 31;
    f32x2 qv = *(const f32x2*)(qg + (size_t)(b * Lq + q0 + r) * Dd + 2 * d2);
    H1 h, lo;
    h.h = pkrtz(qv.x, qv.y);
    lo.h = pkrtz(qv.x - (float)h.h.x, qv.y - (float)h.h.y);
    Qh[r][d2] = h.u;
    Ql[r][d2] = lo.u;
  }
  __syncthreads();

  H8 Bh[2], Bl[2];
#pragma unroll
  for (int s = 0; s < 2; ++s) {
    Bh[s].u4 = *(const u32x4*)&Qh[ln][16 * s + 4 * u];
    Bl[s].u4 = *(const u32x4*)&Ql[ln][16 * s + 4 * u];
  }

  unsigned int su[16][2];
  float rs = 0.f;
#pragma unroll
  for (int t = 0; t < 16; ++t) {
    const float* kr = kg + (size_t)(b * Lq + kb + 16 * t + ln) * Dd + 8 * u;
    f32x4 acc = {0.f, 0.f, 0.f, 0.f};
#pragma unroll
    for (int s = 0; s < 2; ++s) {
      f32x4 k0 = *(const f32x4*)(kr + 32 * s);
      f32x4 k1 = *(const f32x4*)(kr + 32 * s + 4);
      H8 H, L;
      H.h2[0] = pkrtz(k0.x, k0.y);
      H.h2[1] = pkrtz(k0.z, k0.w);
      H.h2[2] = pkrtz(k1.x, k1.y);
      H.h2[3] = pkrtz(k1.z, k1.w);
      L.h2[0] = pkrtz(k0.x - (float)H.h2[0].x, k0.y - (float)H.h2[0].y);
      L.h2[1] = pkrtz(k0.z - (float)H.h2[1].x, k0.w - (float)H.h2[1].y);
      L.h2[2] = pkrtz(k1.x - (float)H.h2[2].x, k1.y - (float)H.h2[2].y);
      L.h2[3] = pkrtz(k1.z - (float)H.h2[3].x, k1.w - (float)H.h2[3].y);
      acc = MF16(H.v8, Bh[s].v8, acc);
      acc = MF16(H.v8, Bl[s].v8, acc);
      acc = MF16(L.v8, Bh[s].v8, acc);
    }
    const int* mp = mg + (size_t)(b * Lq + q0 + ln) * Lq + kb + 16 * t + 4 * u;
    i32x4 mm4 = *(const i32x4*)mp;
    float s0 = mm4.x ? 0.f : acc.x;
    float s1 = mm4.y ? 0.f : acc.y;
    float s2 = mm4.z ? 0.f : acc.z;
    float s3 = mm4.w ? 0.f : acc.w;
    rs += (s0 + s1) + (s2 + s3);
    H1 p0, p1;
    p0.h = pkrtz(s0, s1); p1.h = pkrtz(s2, s3);
    su[t][0] = p0.u; su[t][1] = p1.u;
  }

  rs += __shfl_xor(rs, 16);
  rs += __shfl_xor(rs, 32);
  if (l < 16) red[l][w] = rs;
  __syncthreads();
  f32x4 r0 = *(const f32x4*)&red[ln][0];
  f32x4 r1 = *(const f32x4*)&red[ln][4];
  float sum = ((r0.x + r0.y) + (r0.z + r0.w)) + ((r1.x + r1.y) + (r1.z + r1.w));
  float dinv = 1.0f / fmaxf(sum, 1e-14f);
  if (w == 0 && l < 16) dinv_s[l] = dinv;

#pragma unroll
  for (int t = 0; t < 16; ++t) {
    H1 p0, p1; p0.u = su[t][0]; p1.u = su[t][1];
    f32x4 st = {(float)p0.h.x * dinv, (float)p0.h.y * dinv,
                (float)p1.h.x * dinv, (float)p1.h.y * dinv};
    *(f32x4*)(outA + (size_t)(b * Lq + q0 + ln) * Lq + kb + 16 * t + 4 * u) = st;
  }

  f32x4 pv[4] = {{0,0,0,0},{0,0,0,0},{0,0,0,0},{0,0,0,0}};
#pragma unroll
  for (int g = 0; g < 8; ++g) {
    H8 aw;
    aw.u[0] = su[2 * g][0];     aw.u[1] = su[2 * g][1];
    aw.u[2] = su[2 * g + 1][0]; aw.u[3] = su[2 * g + 1][1];
    const float* vb = vg + (size_t)(b * Lq + kb + 32 * g + 4 * u) * Dd + ln;
#pragma unroll
    for (int nt = 0; nt < 4; ++nt) {
      const float* vp = vb + 16 * nt;
      H8 bw;
      bw.h2[0] = pkrtz(vp[0],       vp[Dd]);
      bw.h2[1] = pkrtz(vp[2 * Dd],  vp[3 * Dd]);
      bw.h2[2] = pkrtz(vp[16 * Dd], vp[17 * Dd]);
      bw.h2[3] = pkrtz(vp[18 * Dd], vp[19 * Dd]);
      pv[nt] = MF16(aw.v8, bw.v8, pv[nt]);
    }
  }

#pragma unroll
  for (int nt = 0; nt < 4; ++nt)
#pragma unroll
    for (int r = 0; r < 4; ++r)
      Ored[w][u * 4 + r][nt * 16 + ln] = pv[nt][r];
  __syncthreads();
  {
    int q = tid >> 5, d = (tid & 31) * 2;
    float o0 = 0.f, o1 = 0.f;
#pragma unroll
    for (int ww = 0; ww < NWAVE; ++ww) {
      o0 += Ored[ww][q][d];
      o1 += Ored[ww][q][d + 1];
    }
    float dv = dinv_s[q];
    f32x2 st = {o0 * dv, o1 * dv};
    *(f32x2*)(outO + (size_t)(b * Lq + q0 + q) * Dd + d) = st;
  }
}

extern "C" void kernel_launch(void* const* d_in, const int* in_sizes, int n_in,
                              void* d_out, int out_size, void* d_ws, size_t ws_size,
                              hipStream_t stream) {
  const float* q = (const float*)d_in[0];
  const float* k = (const float*)d_in[1];
  const float* v = (const float*)d_in[2];
  const int*   m = (const int*)d_in[3];
  float* outO = (float*)d_out;
  float* outA = outO + (size_t)Bb * Lq * Dd;
  dim3 grid(Bb * (Lq / QT));

  if (ws_size >= (12u << 20)) {
    u32x4* Kh = (u32x4*)d_ws;          // 4 MB
    u32x4* Kl = Kh + 262144;           // 4 MB
    u32x4* Vq = Kl + 262144;           // 4 MB
    sdpa_prep<<<2048, 256, 0, stream>>>(k, v, Kh, Kl, Vq);
    sdpa_main<true, true, true, false><<<grid, NT, 0, stream>>>(q, Kh, Kl, Vq, m, outO, outA);
    if (ws_size >= (17u << 20)) {      // ablation variants -> 4MB sink region
      float* sink = (float*)((char*)d_ws + (12u << 20));
      sdpa_main<false, true,  true,  true><<<grid, NT, 0, stream>>>(q, Kh, Kl, Vq, m, sink, sink); // -PV
      sdpa_main<true,  false, true,  true><<<grid, NT, 0, stream>>>(q, Kh, Kl, Vq, m, sink, sink); // -attn store
      sdpa_main<true,  true,  false, true><<<grid, NT, 0, stream>>>(q, Kh, Kl, Vq, m, sink, sink); // -mask load
    }
  } else {
    sdpa_legacy<<<grid, NT, 0, stream>>>(q, k, v, m, outO, outA);
  }
}

// Round 7
// 247.093 us; speedup vs baseline: 3.3155x; 3.3155x over previous
//
#include <hip/hip_runtime.h>

#define Bb 16
#define Lq 2048
#define Dd 64
#define QT 16
#define NT 512
#define NWAVE 8
#define KCH 256

typedef _Float16 f16x2 __attribute__((ext_vector_type(2)));
typedef _Float16 f16x8 __attribute__((ext_vector_type(8)));
typedef __attribute__((ext_vector_type(4))) float f32x4;
typedef __attribute__((ext_vector_type(2))) float f32x2;
typedef __attribute__((ext_vector_type(4))) unsigned int u32x4;
typedef __attribute__((ext_vector_type(2))) unsigned int u32x2;
typedef __attribute__((ext_vector_type(4))) int i32x4;
typedef unsigned long long u64;
typedef __attribute__((ext_vector_type(2))) unsigned long long u64x2;

union H8 { f16x8 v8; f16x2 h2[4]; unsigned int u[4]; u32x4 u4; };
union H1 { f16x2 h; unsigned int u; };

__device__ __forceinline__ f16x2 pkrtz(float a, float b) {
  return __builtin_bit_cast(f16x2, __builtin_amdgcn_cvt_pkrtz(a, b));
}
__device__ __forceinline__ f32x4 MF16(f16x8 a, f16x8 b, f32x4 c) {
  return __builtin_amdgcn_mfma_f32_16x16x32_f16(a, b, c, 0, 0, 0);
}
__device__ __forceinline__ f32x4 MFu(u32x4 a, const H8& b, f32x4 c) {
  return MF16(__builtin_bit_cast(f16x8, a), b.v8, c);
}

// ---------- prep 1: K -> f16 h/l split (A-frag order); V -> B-frag order ----------
__global__ __launch_bounds__(256)
void sdpa_prep_kv(const float* __restrict__ kg, const float* __restrict__ vg,
                  u32x4* __restrict__ Kh, u32x4* __restrict__ Kl,
                  u32x4* __restrict__ Vq)
{
  const int t = threadIdx.x, blk = blockIdx.x;
  if (blk < 1024) {
    const int row = blk * 32 + (t >> 3);
    const int d8  = t & 7;
    const float* kp = kg + (size_t)row * Dd + d8 * 8;
    f32x4 a = *(const f32x4*)kp;
    f32x4 c = *(const f32x4*)(kp + 4);
    H1 h0, h1, h2, h3, l0, l1, l2, l3;
    h0.h = pkrtz(a.x, a.y); l0.h = pkrtz(a.x - (float)h0.h.x, a.y - (float)h0.h.y);
    h1.h = pkrtz(a.z, a.w); l1.h = pkrtz(a.z - (float)h1.h.x, a.w - (float)h1.h.y);
    h2.h = pkrtz(c.x, c.y); l2.h = pkrtz(c.x - (float)h2.h.x, c.y - (float)h2.h.y);
    h3.h = pkrtz(c.z, c.w); l3.h = pkrtz(c.z - (float)h3.h.x, c.w - (float)h3.h.y);
    u32x4 hh = {h0.u, h1.u, h2.u, h3.u};
    u32x4 ll = {l0.u, l1.u, l2.u, l3.u};
    Kh[(size_t)row * 8 + d8] = hh;
    Kl[(size_t)row * 8 + d8] = ll;
  } else {
    const int v_ = (blk - 1024) * 256 + t;
    const int ln = v_ & 15, nt = (v_ >> 4) & 3, u = (v_ >> 6) & 3;
    const int g = (v_ >> 8) & 7, w = (v_ >> 11) & 7, b = v_ >> 14;
    const int R = w * KCH + g * 32 + u * 4;
    const float* vp = vg + ((size_t)b * Lq + R) * Dd + nt * 16 + ln;
    H1 p0, p1, p2, p3;
    p0.h = pkrtz(vp[0 * Dd],  vp[1 * Dd]);
    p1.h = pkrtz(vp[2 * Dd],  vp[3 * Dd]);
    p2.h = pkrtz(vp[16 * Dd], vp[17 * Dd]);
    p3.h = pkrtz(vp[18 * Dd], vp[19 * Dd]);
    u32x4 o = {p0.u, p1.u, p2.u, p3.u};
    Vq[v_] = o;
  }
}

// ---------- prep 2: mask int32 -> bit planes, pure streaming (32:1 compress) ----
// Window = 256 consecutive cols. Per window 4 u64 ballots: word j covers cols
// c == j (mod 4); bit index = c>>2. Main kernel: col 16t+4u+j -> word j, bit 4t+u.
__global__ __launch_bounds__(256)
void sdpa_maskpack(const i32x4* __restrict__ mg4, u64* __restrict__ mb)
{
  const int l  = threadIdx.x & 63;
  const int wg = ((int)blockIdx.x << 2) | (threadIdx.x >> 6);   // 0..8191
  i32x4 cur = mg4[((size_t)wg * 32) * 64 + l];
#pragma unroll 1
  for (int it = 0; it < 32; ++it) {
    i32x4 nxt = {0, 0, 0, 0};
    if (it < 31) nxt = mg4[((size_t)wg * 32 + it + 1) * 64 + l];
    u64 b0 = __ballot(cur.x != 0);
    u64 b1 = __ballot(cur.y != 0);
    u64 b2 = __ballot(cur.z != 0);
    u64 b3 = __ballot(cur.w != 0);
    if (l == 0) {
      u64* o = mb + ((size_t)wg * 32 + it) * 4;
      u64x2 w0 = {b0, b1}, w1 = {b2, b3};
      *(u64x2*)o = w0;
      *(u64x2*)(o + 2) = w1;
    }
    cur = nxt;
  }
}

// ---------------------------- main kernel ----------------------------
__global__ __launch_bounds__(NT, 4)
void sdpa_main(const float* __restrict__ qg,
               const u32x4* __restrict__ Khp, const u32x4* __restrict__ Klp,
               const u32x4* __restrict__ Vqp, const u64* __restrict__ mbp,
               float* __restrict__ outO, float* __restrict__ outA)
{
  __shared__ unsigned int Qh[QT][36], Ql[QT][36];     // 4.6 KB
  __shared__ float red[QT][NWAVE];
  __shared__ float dinv_s[QT];
  __shared__ unsigned short SBIG[NWAVE][QT][256];     // 64 KB S-transpose; aliased by Ored

  const int tid = threadIdx.x;
  const int l   = tid & 63;
  const int ln  = l & 15;
  const int u   = l >> 4;
  const int w   = tid >> 6;
  const int bid = (int)(blockIdx.x % 8) * 256 + (int)(blockIdx.x / 8);
  const int b   = bid >> 7;
  const int q0  = (bid & 127) * QT;
  const int kb  = w * KCH;

  // Phase 0: Q -> f16 h/l split planes in LDS
  {
    int r = tid >> 5, d2 = tid & 31;
    f32x2 qv = *(const f32x2*)(qg + (size_t)(b * Lq + q0 + r) * Dd + 2 * d2);
    H1 h, lo;
    h.h  = pkrtz(qv.x, qv.y);
    lo.h = pkrtz(qv.x - (float)h.h.x, qv.y - (float)h.h.y);
    Qh[r][d2] = h.u;
    Ql[r][d2] = lo.u;
  }
  __syncthreads();

  H8 Bh[2], Bl[2];
#pragma unroll
  for (int s = 0; s < 2; ++s) {
    Bh[s].u4 = *(const u32x4*)&Qh[ln][16 * s + 4 * u];
    Bl[s].u4 = *(const u32x4*)&Ql[ln][16 * s + 4 * u];
  }

  // mask bit-planes for (row ln, window w): 4 u64s = 32B, quad-broadcast
  const u64* mrow = mbp + ((size_t)(b * Lq + q0 + ln) * 8 + w) * 4;
  const u32x4 MB0 = *(const u32x4*)mrow;        // B0lo B0hi B1lo B1hi
  const u32x4 MB1 = *(const u32x4*)(mrow + 2);  // B2lo B2hi B3lo B3hi

  // Phase 1: S = K.Q^T (hh+hl+lh), mask from regs, S -> regs + LDS transpose buf
  const u32x4* khB = Khp + ((size_t)b * Lq + kb + ln) * 8 + u;
  const u32x4* klB = Klp + ((size_t)b * Lq + kb + ln) * 8 + u;

  unsigned int su[16][2];
  float rs = 0.f;
  u32x4 nh0 = khB[0], nh1 = khB[4];
  u32x4 nl0 = klB[0], nl1 = klB[4];

#pragma unroll
  for (int t = 0; t < 16; ++t) {
    u32x4 h0 = nh0, h1 = nh1, l0 = nl0, l1 = nl1;
    if (t < 15) {
      nh0 = khB[128 * (t + 1)];  nh1 = khB[128 * (t + 1) + 4];
      nl0 = klB[128 * (t + 1)];  nl1 = klB[128 * (t + 1) + 4];
    }
    f32x4 acc = {0.f, 0.f, 0.f, 0.f};
    acc = MFu(h0, Bh[0], acc);
    acc = MFu(h0, Bl[0], acc);
    acc = MFu(l0, Bh[0], acc);
    acc = MFu(h1, Bh[1], acc);
    acc = MFu(h1, Bl[1], acc);
    acc = MFu(l1, Bh[1], acc);
    // col c = 16t+4u+j -> ballot word j, bit 4t+u (u32 half & shift compile-time by t)
    const int sh = 4 * (t & 7) + u;
    unsigned m0, m1, m2, m3;
    if (t < 8) { m0 = MB0.x; m1 = MB0.z; m2 = MB1.x; m3 = MB1.z; }
    else       { m0 = MB0.y; m1 = MB0.w; m2 = MB1.y; m3 = MB1.w; }
    float s0 = ((m0 >> sh) & 1u) ? 0.f : acc.x;
    float s1 = ((m1 >> sh) & 1u) ? 0.f : acc.y;
    float s2 = ((m2 >> sh) & 1u) ? 0.f : acc.z;
    float s3 = ((m3 >> sh) & 1u) ? 0.f : acc.w;
    rs += (s0 + s1) + (s2 + s3);
    H1 p0, p1;
    p0.h = pkrtz(s0, s1); p1.h = pkrtz(s2, s3);
    su[t][0] = p0.u; su[t][1] = p1.u;
    // stream S into per-wave LDS transpose buffer (XOR-swizzled b64 write)
    unsigned off = (unsigned)((16 * t + 4 * u) * 2) ^ (unsigned)((ln & 7) << 4);
    u32x2 pk2 = {p0.u, p1.u};
    *(u32x2*)((char*)&SBIG[w][ln][0] + off) = pk2;
  }

  // Phase 2: row-sum -> dinv (per-lane, row = ln)
  rs += __shfl_xor(rs, 16);
  rs += __shfl_xor(rs, 32);
  if (l < 16) red[l][w] = rs;
  __syncthreads();
  f32x4 r0 = *(const f32x4*)&red[ln][0];
  f32x4 r1 = *(const f32x4*)&red[ln][4];
  float sum = ((r0.x + r0.y) + (r0.z + r0.w)) + ((r1.x + r1.y) + (r1.z + r1.w));
  float dinv = 1.0f / fmaxf(sum, 1e-14f);
  if (w == 0 && l < 16) dinv_s[l] = dinv;

  // Phase 3: attn stores — 1KB-contiguous bursts per row from own LDS buffer
  {
    float* arow = outA + (size_t)(b * Lq + q0) * Lq + kb;
#pragma unroll
    for (int r = 0; r < 16; ++r) {
      float dv = __shfl(dinv, r);          // lane r holds row r's dinv
      unsigned off = (unsigned)(8 * l) ^ (unsigned)((r & 7) << 4);
      u32x2 pk = *(const u32x2*)((char*)&SBIG[w][r][0] + off);
      H1 a0, a1; a0.u = pk.x; a1.u = pk.y;
      f32x4 st = {(float)a0.h.x * dv, (float)a0.h.y * dv,
                  (float)a1.h.x * dv, (float)a1.h.y * dv};
      *(f32x4*)(arow + (size_t)r * Lq + 4 * l) = st;
    }
  }

  // Phase 4: PV via prepacked Vq (coalesced dwordx4), S from registers
  f32x4 pv[4] = {{0,0,0,0},{0,0,0,0},{0,0,0,0},{0,0,0,0}};
  {
    const u32x4* vq = Vqp + (size_t)(b * 8 + w) * 2048;
#pragma unroll
    for (int g = 0; g < 8; ++g) {
      H8 aw;
      aw.u[0] = su[2 * g][0];     aw.u[1] = su[2 * g][1];
      aw.u[2] = su[2 * g + 1][0]; aw.u[3] = su[2 * g + 1][1];
#pragma unroll
      for (int nt = 0; nt < 4; ++nt) {
        u32x4 bw = vq[((g * 4 + u) * 4 + nt) * 16 + ln];
        pv[nt] = MF16(aw.v8, __builtin_bit_cast(f16x8, bw), pv[nt]);
      }
    }
  }

  // Phase 5: cross-wave O reduce (Ored aliases SBIG — all S reads done) + store
  __syncthreads();                         // all SBIG attn reads complete
  float (*Ored)[QT][66] = (float (*)[QT][66])SBIG;
#pragma unroll
  for (int nt = 0; nt < 4; ++nt)
#pragma unroll
    for (int r = 0; r < 4; ++r)
      Ored[w][u * 4 + r][nt * 16 + ln] = pv[nt][r];
  __syncthreads();
  {
    int q = tid >> 5, d = (tid & 31) * 2;
    float o0 = 0.f, o1 = 0.f;
#pragma unroll
    for (int ww = 0; ww < NWAVE; ++ww) {
      o0 += Ored[ww][q][d];
      o1 += Ored[ww][q][d + 1];
    }
    float dv = dinv_s[q];
    f32x2 st = {o0 * dv, o1 * dv};
    *(f32x2*)(outO + (size_t)(b * Lq + q0 + q) * Dd + d) = st;
  }
}

// ---------------- legacy fallback (R5 kernel, known-passing) ----------------
__global__ __launch_bounds__(NT, 4)
void sdpa_legacy(const float* __restrict__ qg, const float* __restrict__ kg,
                 const float* __restrict__ vg, const int* __restrict__ mg,
                 float* __restrict__ outO, float* __restrict__ outA)
{
  __shared__ unsigned int Qh[QT][36], Ql[QT][36];
  __shared__ float red[QT][NWAVE];
  __shared__ float dinv_s[QT];
  __shared__ float Ored[NWAVE][QT][66];

  const int tid = threadIdx.x;
  const int l   = tid & 63;
  const int ln  = l & 15;
  const int u   = l >> 4;
  const int w   = tid >> 6;
  const int bid = (int)(blockIdx.x % 8) * 256 + (int)(blockIdx.x / 8);
  const int b   = bid >> 7;
  const int q0  = (bid & 127) * QT;
  const int kb  = w * KCH;

  {
    int r = tid >> 5, d2 = tid & 31;
    f32x2 qv = *(const f32x2*)(qg + (size_t)(b * Lq + q0 + r) * Dd + 2 * d2);
    H1 h, lo;
    h.h = pkrtz(qv.x, qv.y);
    lo.h = pkrtz(qv.x - (float)h.h.x, qv.y - (float)h.h.y);
    Qh[r][d2] = h.u;
    Ql[r][d2] = lo.u;
  }
  __syncthreads();

  H8 Bh[2], Bl[2];
#pragma unroll
  for (int s = 0; s < 2; ++s) {
    Bh[s].u4 = *(const u32x4*)&Qh[ln][16 * s + 4 * u];
    Bl[s].u4 = *(const u32x4*)&Ql[ln][16 * s + 4 * u];
  }

  unsigned int su[16][2];
  float rs = 0.f;
#pragma unroll
  for (int t = 0; t < 16; ++t) {
    const float* kr = kg + (size_t)(b * Lq + kb + 16 * t + ln) * Dd + 8 * u;
    f32x4 acc = {0.f, 0.f, 0.f, 0.f};
#pragma unroll
    for (int s = 0; s < 2; ++s) {
      f32x4 k0 = *(const f32x4*)(kr + 32 * s);
      f32x4 k1 = *(const f32x4*)(kr + 32 * s + 4);
      H8 H, L;
      H.h2[0] = pkrtz(k0.x, k0.y);
      H.h2[1] = pkrtz(k0.z, k0.w);
      H.h2[2] = pkrtz(k1.x, k1.y);
      H.h2[3] = pkrtz(k1.z, k1.w);
      L.h2[0] = pkrtz(k0.x - (float)H.h2[0].x, k0.y - (float)H.h2[0].y);
      L.h2[1] = pkrtz(k0.z - (float)H.h2[1].x, k0.w - (float)H.h2[1].y);
      L.h2[2] = pkrtz(k1.x - (float)H.h2[2].x, k1.y - (float)H.h2[2].y);
      L.h2[3] = pkrtz(k1.z - (float)H.h2[3].x, k1.w - (float)H.h2[3].y);
      acc = MF16(H.v8, Bh[s].v8, acc);
      acc = MF16(H.v8, Bl[s].v8, acc);
      acc = MF16(L.v8, Bh[s].v8, acc);
    }
    const int* mp = mg + (size_t)(b * Lq + q0 + ln) * Lq + kb + 16 * t + 4 * u;
    i32x4 mm4 = *(const i32x4*)mp;
    float s0 = mm4.x ? 0.f : acc.x;
    float s1 = mm4.y ? 0.f : acc.y;
    float s2 = mm4.z ? 0.f : acc.z;
    float s3 = mm4.w ? 0.f : acc.w;
    rs += (s0 + s1) + (s2 + s3);
    H1 p0, p1;
    p0.h = pkrtz(s0, s1); p1.h = pkrtz(s2, s3);
    su[t][0] = p0.u; su[t][1] = p1.u;
  }

  rs += __shfl_xor(rs, 16);
  rs += __shfl_xor(rs, 32);
  if (l < 16) red[l][w] = rs;
  __syncthreads();
  f32x4 r0 = *(const f32x4*)&red[ln][0];
  f32x4 r1 = *(const f32x4*)&red[ln][4];
  float sum = ((r0.x + r0.y) + (r0.z + r0.w)) + ((r1.x + r1.y) + (r1.z + r1.w));
  float dinv = 1.0f / fmaxf(sum, 1e-14f);
  if (w == 0 && l < 16) dinv_s[l] = dinv;

#pragma unroll
  for (int t = 0; t < 16; ++t) {
    H1 p0, p1; p0.u = su[t][0]; p1.u = su[t][1];
    f32x4 st = {(float)p0.h.x * dinv, (float)p0.h.y * dinv,
                (float)p1.h.x * dinv, (float)p1.h.y * dinv};
    *(f32x4*)(outA + (size_t)(b * Lq + q0 + ln) * Lq + kb + 16 * t + 4 * u) = st;
  }

  f32x4 pv[4] = {{0,0,0,0},{0,0,0,0},{0,0,0,0},{0,0,0,0}};
#pragma unroll
  for (int g = 0; g < 8; ++g) {
    H8 aw;
    aw.u[0] = su[2 * g][0];     aw.u[1] = su[2 * g][1];
    aw.u[2] = su[2 * g + 1][0]; aw.u[3] = su[2 * g + 1][1];
    const float* vb = vg + (size_t)(b * Lq + kb + 32 * g + 4 * u) * Dd + ln;
#pragma unroll
    for (int nt = 0; nt < 4; ++nt) {
      const float* vp = vb + 16 * nt;
      H8 bw;
      bw.h2[0] = pkrtz(vp[0],       vp[Dd]);
      bw.h2[1] = pkrtz(vp[2 * Dd],  vp[3 * Dd]);
      bw.h2[2] = pkrtz(vp[16 * Dd], vp[17 * Dd]);
      bw.h2[3] = pkrtz(vp[18 * Dd], vp[19 * Dd]);
      pv[nt] = MF16(aw.v8, bw.v8, pv[nt]);
    }
  }

#pragma unroll
  for (int nt = 0; nt < 4; ++nt)
#pragma unroll
    for (int r = 0; r < 4; ++r)
      Ored[w][u * 4 + r][nt * 16 + ln] = pv[nt][r];
  __syncthreads();
  {
    int q = tid >> 5, d = (tid & 31) * 2;
    float o0 = 0.f, o1 = 0.f;
#pragma unroll
    for (int ww = 0; ww < NWAVE; ++ww) {
      o0 += Ored[ww][q][d];
      o1 += Ored[ww][q][d + 1];
    }
    float dv = dinv_s[q];
    f32x2 st = {o0 * dv, o1 * dv};
    *(f32x2*)(outO + (size_t)(b * Lq + q0 + q) * Dd + d) = st;
  }
}

extern "C" void kernel_launch(void* const* d_in, const int* in_sizes, int n_in,
                              void* d_out, int out_size, void* d_ws, size_t ws_size,
                              hipStream_t stream) {
  const float* q = (const float*)d_in[0];
  const float* k = (const float*)d_in[1];
  const float* v = (const float*)d_in[2];
  const int*   m = (const int*)d_in[3];
  float* outO = (float*)d_out;
  float* outA = outO + (size_t)Bb * Lq * Dd;
  dim3 grid(Bb * (Lq / QT));

  if (ws_size >= (20u << 20)) {
    u32x4* Kh = (u32x4*)d_ws;                         // 4 MB
    u32x4* Kl = Kh + 262144;                          // 4 MB
    u32x4* Vq = Kl + 262144;                          // 4 MB
    u64*   mb = (u64*)((char*)d_ws + (12u << 20));    // 8 MB bit-planes
    sdpa_prep_kv<<<2048, 256, 0, stream>>>(k, v, Kh, Kl, Vq);
    sdpa_maskpack<<<2048, 256, 0, stream>>>((const i32x4*)m, mb);
    sdpa_main<<<grid, NT, 0, stream>>>(q, Kh, Kl, Vq, mb, outO, outA);
  } else {
    sdpa_legacy<<<grid, NT, 0, stream>>>(q, k, v, m, outO, outA);
  }
}